// Round 2
// baseline (2968.662 us; speedup 1.0000x reference)
//
#include <hip/hip_runtime.h>
#include <hip/hip_bf16.h>

// Swin-V2 window attention, fully fused per window.
// B=2048 windows, N=64 tokens, CH=512, H=16 heads, d=32, NW=256 masks.
// Round 2: cooperative per-head (4 waves split rows), shared 14.8KB scratch,
// XOR-swizzled x tile (no padding), LDS 80384B + VGPR<=256 -> 2 blocks/CU.
//
// ws layout (2.38 MB):
//   [0)        bias_tab f32 [16][64][64]   = 262144 B
//   [262144)   wqkv_t  bf16 [1536][512]    = 1572864 B  (w_qkv transposed)
//   [1835008)  proj_t  bf16 [512][512]     = 524288 B   (proj_w transposed)
//   [2359296)  tab225  f32 [225][16]       = 14400 B

typedef __attribute__((ext_vector_type(4))) float f32x4;
typedef __attribute__((ext_vector_type(8))) __bf16 bf16x8;

#define MFMA16(a, b, c) __builtin_amdgcn_mfma_f32_16x16x32_bf16((a), (b), (c), 0, 0, 0)

__device__ __forceinline__ unsigned short f2bf(float f) {
  union { float f; unsigned u; } v; v.f = f;
  unsigned r = v.u + 0x7fffu + ((v.u >> 16) & 1u);   // round-to-nearest-even
  return (unsigned short)(r >> 16);
}

// ---------------------------------------------------------------- prep1
__global__ void prep1(const float* __restrict__ rel_table,
                      const float* __restrict__ w_qkv,
                      const float* __restrict__ proj_w,
                      const float* __restrict__ cpb_w1,
                      const float* __restrict__ cpb_b1,
                      const float* __restrict__ cpb_w2,
                      unsigned short* __restrict__ wqkv_t,
                      unsigned short* __restrict__ proj_t,
                      float* __restrict__ tab225) {
  const int bid = blockIdx.x, tid = threadIdx.x;
  __shared__ float red[4][16];
  if (bid < 225) {
    const float t0 = rel_table[bid * 2], t1 = rel_table[bid * 2 + 1];
    float acc[16];
#pragma unroll
    for (int h = 0; h < 16; ++h) acc[h] = 0.f;
    for (int j = tid; j < 512; j += 256) {
      const float hj = fmaxf(t0 * cpb_w1[j] + t1 * cpb_w1[512 + j] + cpb_b1[j], 0.f);
#pragma unroll
      for (int h = 0; h < 16; ++h) acc[h] += hj * cpb_w2[j * 16 + h];
    }
    const int lane = tid & 63, w = tid >> 6;
#pragma unroll
    for (int h = 0; h < 16; ++h) {
      float v = acc[h];
      for (int m = 1; m < 64; m <<= 1) v += __shfl_xor(v, m);
      if (lane == 0) red[w][h] = v;
    }
    __syncthreads();
    if (tid < 16)
      tab225[bid * 16 + tid] = red[0][tid] + red[1][tid] + red[2][tid] + red[3][tid];
  } else if (bid < 225 + 1536) {
    const int n = bid - 225;
    for (int k = tid; k < 512; k += 256)
      wqkv_t[n * 512 + k] = f2bf(w_qkv[(size_t)k * 1536 + n]);
  } else {
    const int n = bid - 1761;
    for (int k = tid; k < 512; k += 256)
      proj_t[n * 512 + k] = f2bf(proj_w[(size_t)k * 512 + n]);
  }
}

// ---------------------------------------------------------------- prep2
__global__ void prep2(const float* __restrict__ tab225, float* __restrict__ bias_tab) {
  const int h = blockIdx.x, tid = threadIdx.x;
  for (int e = tid; e < 4096; e += 256) {
    const int n = e >> 6, m = e & 63;
    const int dr = (n >> 3) - (m >> 3) + 7;
    const int dc = (n & 7) - (m & 7) + 7;
    const float v = tab225[(dr * 15 + dc) * 16 + h];
    bias_tab[h * 4096 + e] = 16.f / (1.f + __expf(-v));
  }
}

// ---------------------------------------------------------------- main fused kernel
// LDS map (80384 B total):
//   x_s [64][512] bf16, XOR-swizzled 8-elem chunks             65536 B
//   scr (14848 B):
//     q_s  = scr+0     [64][40]  (Qn, rows=tokens)              5120 B
//     k_s  = scr+2560  [64][40]  (Kn)                           5120 B
//     v_s  = scr+5120  [32][72]  (V^T, rows=d, cols=tokens)     4608 B
//     p_s  = scr+0     [64][72]  P overlays q+k (dead then)     9216 B
//     o_s  = scr+1152*w [16][40] O overlays OWN P slice only    1280 B/wave
// Barriers: 3 per head (bar_A top, bar_1 after qkv write, bar_2 before P write).
__global__ __launch_bounds__(256, 2) void win_attn_fused(
    const float* __restrict__ x,
    const float* __restrict__ mask,
    const float* __restrict__ q_bias,
    const float* __restrict__ v_bias,
    const float* __restrict__ logit_scale,
    const float* __restrict__ proj_b,
    const unsigned short* __restrict__ wqkv_t,
    const unsigned short* __restrict__ proj_t,
    const float* __restrict__ bias_tab,
    float* __restrict__ out) {
  __shared__ __align__(16) unsigned short x_s[64 * 512];  // 65536 B
  __shared__ __align__(16) unsigned short scr[7424];      // 14848 B

  const int tid = threadIdx.x;
  const int w = tid >> 6;      // wave id 0..3
  const int lane = tid & 63;
  const int c16 = lane & 15;   // MFMA A-row / B-col / C-col
  const int g = lane >> 4;     // MFMA k-group / C-row quad
  const int b = blockIdx.x;
  const int rw = 16 * w;       // this wave's row base (M-split)

  // Phase 0: stage x window as bf16 into LDS, XOR-swizzled 16B chunks.
  {
    const float4* xg = (const float4*)(x + (size_t)b * (64 * 512));
#pragma unroll
    for (int it = 0; it < 32; ++it) {
      const int e4 = it * 256 + tid;
      const float4 v4 = xg[e4];
      const int r = e4 >> 7;        // token row (128 float4 per row)
      const int k4 = e4 & 127;      // float4 index within row
      const int sw = ((((k4 >> 1) ^ (r & 7)) << 3) | ((k4 & 1) << 2));
      ushort4 pk;
      pk.x = f2bf(v4.x); pk.y = f2bf(v4.y); pk.z = f2bf(v4.z); pk.w = f2bf(v4.w);
      *(ushort4*)&x_s[r * 512 + sw] = pk;
    }
  }

  unsigned short* q_s = scr;
  unsigned short* k_s = scr + 2560;
  unsigned short* v_s = scr + 5120;
  unsigned short* p_s = scr;
  unsigned short* o_s = scr + 1152 * w;

  const f32x4 z = {0.f, 0.f, 0.f, 0.f};
  f32x4 oa[32];
#pragma unroll
  for (int i = 0; i < 32; ++i) oa[i] = z;

  for (int h = 0; h < 16; ++h) {
    __syncthreads();  // bar_A: prev head's LDS reads done; x_s ready (h=0)
    const float scale_h = __expf(fminf(logit_scale[h], 4.6051701859880914f));
    const unsigned short* wq = wqkv_t + (size_t)(h * 32) * 512;
    const unsigned short* wk = wqkv_t + (size_t)(512 + h * 32) * 512;
    const unsigned short* wv = wqkv_t + (size_t)(1024 + h * 32) * 512;

    // ---- Stage A: rows [rw,rw+16) of Q,K,V[64,32] = x @ Wqkv_h (96 MFMA/wave)
    f32x4 aq[2], ak[2], av[2];
    aq[0] = aq[1] = ak[0] = ak[1] = av[0] = av[1] = z;
    const int axbase = (rw + c16) * 512;
    const int as = c16 & 7;   // swizzle key for A rows (rw multiple of 16)
#pragma unroll
    for (int ks = 0; ks < 16; ++ks) {
      const bf16x8 A = *(const bf16x8*)&x_s[axbase + (((ks * 4 + g) ^ as) << 3)];
#pragma unroll
      for (int nt = 0; nt < 2; ++nt) {
        const int ro = (nt * 16 + c16) * 512 + ks * 32 + g * 8;
        const bf16x8 Bq = *(const bf16x8*)&wq[ro];
        const bf16x8 Bk = *(const bf16x8*)&wk[ro];
        const bf16x8 Bv = *(const bf16x8*)&wv[ro];
        aq[nt] = MFMA16(A, Bq, aq[nt]);
        ak[nt] = MFMA16(A, Bk, ak[nt]);
        av[nt] = MFMA16(A, Bv, av[nt]);
      }
    }
    // bias add, row-normalize Q (x scale_h) and K, write Qn/Kn/V^T to shared
    const float qb0 = q_bias[h * 32 + c16], qb1 = q_bias[h * 32 + 16 + c16];
    const float vb0 = v_bias[h * 32 + c16], vb1 = v_bias[h * 32 + 16 + c16];
#pragma unroll
    for (int j = 0; j < 4; ++j) {
      const int r = rw + 4 * g + j;  // C layout: row = (lane>>4)*4 + reg
      float q0 = aq[0][j] + qb0, q1 = aq[1][j] + qb1;
      float ss = q0 * q0 + q1 * q1;
      ss += __shfl_xor(ss, 1); ss += __shfl_xor(ss, 2);
      ss += __shfl_xor(ss, 4); ss += __shfl_xor(ss, 8);
      const float rn = scale_h * rsqrtf(ss);
      q_s[r * 40 + c16] = f2bf(q0 * rn);
      q_s[r * 40 + 16 + c16] = f2bf(q1 * rn);
      const float k0 = ak[0][j], k1 = ak[1][j];
      float sk = k0 * k0 + k1 * k1;
      sk += __shfl_xor(sk, 1); sk += __shfl_xor(sk, 2);
      sk += __shfl_xor(sk, 4); sk += __shfl_xor(sk, 8);
      const float rk = rsqrtf(sk);
      k_s[r * 40 + c16] = f2bf(k0 * rk);
      k_s[r * 40 + 16 + c16] = f2bf(k1 * rk);
      v_s[c16 * 72 + r] = f2bf(av[0][j] + vb0);          // V^T[d][token]
      v_s[(16 + c16) * 72 + r] = f2bf(av[1][j] + vb1);
    }
    __syncthreads();  // bar_1: all Qn/Kn/V^T visible

    // ---- Stage B: S rows [rw,rw+16) x 64 = Qn @ Kn^T (4 MFMA), +bias+mask, softmax
    f32x4 S[4];
    {
      const bf16x8 Aq = *(const bf16x8*)&q_s[(rw + c16) * 40 + g * 8];
#pragma unroll
      for (int nt = 0; nt < 4; ++nt) {
        const bf16x8 Bk = *(const bf16x8*)&k_s[(nt * 16 + c16) * 40 + g * 8];
        S[nt] = MFMA16(Aq, Bk, z);
      }
    }
    const float* bt = bias_tab + (size_t)h * 4096;
    const float* mk = mask + (size_t)(b & 255) * 4096;
#pragma unroll
    for (int j = 0; j < 4; ++j) {
      const int r = rw + 4 * g + j;
#pragma unroll
      for (int nt = 0; nt < 4; ++nt)
        S[nt][j] += bt[r * 64 + nt * 16 + c16] + mk[r * 64 + nt * 16 + c16];
      float m0 = fmaxf(fmaxf(S[0][j], S[1][j]), fmaxf(S[2][j], S[3][j]));
      m0 = fmaxf(m0, __shfl_xor(m0, 1));
      m0 = fmaxf(m0, __shfl_xor(m0, 2));
      m0 = fmaxf(m0, __shfl_xor(m0, 4));
      m0 = fmaxf(m0, __shfl_xor(m0, 8));
      float sum = 0.f;
#pragma unroll
      for (int nt = 0; nt < 4; ++nt) {
        const float p = __expf(S[nt][j] - m0);
        S[nt][j] = p;
        sum += p;
      }
      sum += __shfl_xor(sum, 1); sum += __shfl_xor(sum, 2);
      sum += __shfl_xor(sum, 4); sum += __shfl_xor(sum, 8);
      const float inv = 1.f / sum;
#pragma unroll
      for (int nt = 0; nt < 4; ++nt) S[nt][j] *= inv;
    }
    __syncthreads();  // bar_2: all q/k LDS reads done before P overlays them
#pragma unroll
    for (int j = 0; j < 4; ++j) {
      const int r = rw + 4 * g + j;
#pragma unroll
      for (int nt = 0; nt < 4; ++nt)
        p_s[r * 72 + nt * 16 + c16] = f2bf(S[nt][j]);
    }

    // ---- Stage C: O rows [rw,rw+16) = P @ V (4 MFMA); P own rows, V^T shared
    f32x4 O2[2];
    O2[0] = O2[1] = z;
#pragma unroll
    for (int ks = 0; ks < 2; ++ks) {
      const bf16x8 Ap = *(const bf16x8*)&p_s[(rw + c16) * 72 + ks * 32 + g * 8];
#pragma unroll
      for (int nt = 0; nt < 2; ++nt) {
        const bf16x8 Bv = *(const bf16x8*)&v_s[(nt * 16 + c16) * 72 + ks * 32 + g * 8];
        O2[nt] = MFMA16(Ap, Bv, O2[nt]);
      }
    }
    // O -> own P slice (no barrier: only this wave reads/writes this slice)
#pragma unroll
    for (int j = 0; j < 4; ++j) {
      const int rl = 4 * g + j;
#pragma unroll
      for (int nt = 0; nt < 2; ++nt)
        o_s[rl * 40 + nt * 16 + c16] = f2bf(O2[nt][j]);
    }

    // ---- Stage D: outacc[rows rw..rw+16, all 512 cols] += O_h @ proj_w[h*32:,:]
    {
      const bf16x8 Ao = *(const bf16x8*)&o_s[c16 * 40 + g * 8];  // own rows
      const int koff = h * 32 + g * 8;
#pragma unroll
      for (int nt = 0; nt < 32; ++nt) {
        const bf16x8 B = *(const bf16x8*)&proj_t[(size_t)(nt * 16 + c16) * 512 + koff];
        oa[nt] = MFMA16(Ao, B, oa[nt]);
      }
    }
  }

  // ---- epilogue: + proj_b, store f32 (rows rw..rw+16, all 512 cols)
  float* og = out + (size_t)b * (64 * 512);
#pragma unroll
  for (int j = 0; j < 4; ++j) {
    const int r = rw + 4 * g + j;
#pragma unroll
    for (int nt = 0; nt < 32; ++nt) {
      const int c = nt * 16 + c16;
      og[r * 512 + c] = oa[nt][j] + proj_b[c];
    }
  }
}

// ---------------------------------------------------------------- launch
extern "C" void kernel_launch(void* const* d_in, const int* in_sizes, int n_in,
                              void* d_out, int out_size, void* d_ws, size_t ws_size,
                              hipStream_t stream) {
  const float* x = (const float*)d_in[0];
  const float* mask = (const float*)d_in[1];
  const float* rel_table = (const float*)d_in[2];
  const float* w_qkv = (const float*)d_in[3];
  const float* q_bias = (const float*)d_in[4];
  const float* v_bias = (const float*)d_in[5];
  const float* logit_scale = (const float*)d_in[6];
  const float* cpb_w1 = (const float*)d_in[7];
  const float* cpb_b1 = (const float*)d_in[8];
  const float* cpb_w2 = (const float*)d_in[9];
  const float* proj_w = (const float*)d_in[10];
  const float* proj_b = (const float*)d_in[11];

  char* ws = (char*)d_ws;
  float* bias_tab = (float*)(ws);
  unsigned short* wqkv_t = (unsigned short*)(ws + 262144);
  unsigned short* proj_t = (unsigned short*)(ws + 262144 + 1572864);
  float* tab225 = (float*)(ws + 262144 + 1572864 + 524288);

  prep1<<<2273, 256, 0, stream>>>(rel_table, w_qkv, proj_w, cpb_w1, cpb_b1, cpb_w2,
                                  wqkv_t, proj_t, tab225);
  prep2<<<16, 256, 0, stream>>>(tab225, bias_tab);
  win_attn_fused<<<2048, 256, 0, stream>>>(x, mask, q_bias, v_bias, logit_scale, proj_b,
                                           wqkv_t, proj_t, bias_tab, (float*)d_out);
}